// Round 3
// baseline (267.622 us; speedup 1.0000x reference)
//
#include <hip/hip_runtime.h>

// Problem constants
#define BB   128
#define DD   2048
#define NN   2048
#define LL   4
#define OUTN 1024
#define JBQ  32                // 16-k groups per K-quarter (512 k / quarter)
#define NDIG 7                 // base-128 digit planes (sign-safe for i8 MFMA)

typedef double double4v __attribute__((ext_vector_type(4)));
typedef int    int4v    __attribute__((ext_vector_type(4)));
typedef char   char4v   __attribute__((ext_vector_type(4)));

// ---------------------------------------------------------------------------
// Layer-0 transpose-gather: At[k][b] = x[b, axon_idx0[k]]
// ---------------------------------------------------------------------------
__global__ __launch_bounds__(256) void gather0_kernel(
    const float* __restrict__ x, const int* __restrict__ idx0,
    float* __restrict__ At)
{
    int i = blockIdx.x * 256 + threadIdx.x;   // over DD*BB
    int k = i >> 7;
    int b = i & 127;
    At[i] = x[b * DD + idx0[k]];
}

// ---------------------------------------------------------------------------
// W digitization (one layer): W fp32 -> 7 NON-NEGATIVE base-128 digit planes
// of V' = rint(W * 2^48) + 2^47  (V' in [0,2^48), u_j in [0,127]).
// Digits are valid under BOTH signed and unsigned i8 MFMA semantics.
// Bias removal happens in the layer kernel via a constant ones-plane chain.
// Plane layout: Wd[j][n][k], j = 0..6.
// ---------------------------------------------------------------------------
__global__ __launch_bounds__(256) void wdig7_kernel(
    const float* __restrict__ Wl, signed char* __restrict__ Wd)
{
    const size_t DP = (size_t)NN * DD;
    size_t i  = (size_t)blockIdx.x * 256 + threadIdx.x;   // one float4 per thread
    size_t r4 = i * 4;
    float4 w = *(const float4*)(Wl + r4);
    const float wv[4] = {w.x, w.y, w.z, w.w};
    unsigned long long V[4];
    #pragma unroll
    for (int e = 0; e < 4; ++e)
        V[e] = (unsigned long long)(__double2ll_rn((double)wv[e] * 0x1p48)
                                    + (1LL << 47));
    #pragma unroll
    for (int j = 0; j < NDIG; ++j) {
        char4v p = { (char)((V[0] >> (7 * j)) & 127),
                     (char)((V[1] >> (7 * j)) & 127),
                     (char)((V[2] >> (7 * j)) & 127),
                     (char)((V[3] >> (7 * j)) & 127) };
        *(char4v*)(Wd + (size_t)j * DP + r4) = p;
    }
}

// ---------------------------------------------------------------------------
// Per-layer spike gather (layers 1..3): g8T[b][k] = c8T[b][idx[k]]  (i8 counts)
// ---------------------------------------------------------------------------
__global__ __launch_bounds__(256) void gather8_kernel(
    const signed char* __restrict__ c8T, const int* __restrict__ idx,
    signed char* __restrict__ g8T)
{
    int i = blockIdx.x * 256 + threadIdx.x;   // over BB*DD
    int b = i >> 11;
    int k = i & (DD - 1);
    g8T[i] = c8T[(size_t)b * DD + idx[k]];
}

// ---------------------------------------------------------------------------
// Barrier-free fused layer kernel, fp64 MFMA path (layer 0 / fallback).
// Proven structure; optional i8 count emission (c8T[b][n]) for the i8 path.
// ---------------------------------------------------------------------------
__global__ __launch_bounds__(256, 2) void layer_kernel(
    const float* __restrict__ srcT,   // [2048 rows][BB] fp32
    const int*   __restrict__ idx,    // nullptr => identity rows
    const float* __restrict__ Wl,     // [n][k] row-major
    const float* __restrict__ thresholds, int l,
    const int*   __restrict__ Tptr,
    float* __restrict__ dst, signed char* __restrict__ c8T, int isLast)
{
    __shared__ double red[4 * 64 * 8];   // 16 KB, epilogue only

    const int t    = threadIdx.x;
    const int wq   = t >> 6;             // K-quarter 0..3
    const int lane = t & 63;
    const int q    = lane >> 4;
    const int c    = lane & 15;

    const int g     = blockIdx.x;        // 0..511
    const int btile = (g >> 3) & 7;      // b-replicas of one nsup: same XCD (mod 8)
    const int nsup  = (g & 7) | ((g >> 6) << 3);
    const int n0    = nsup * 32;
    const int bcol  = btile * 16 + c;

    // ---- runtime D-layout probe (layout-agnostic epilogue), f64-native ----
    double4v pr = {0., 0., 0., 0.}, pcv = {0., 0., 0., 0.};
    pr  = __builtin_amdgcn_mfma_f64_16x16x4f64(0.25 * (double)c, 1.0, pr, 0, 0, 0);
    pcv = __builtin_amdgcn_mfma_f64_16x16x4f64(0.25, (double)c, pcv, 0, 0, 0);
    int rowD[4], colD[4];
    #pragma unroll
    for (int r = 0; r < 4; ++r) {
        rowD[r] = (int)(pr[r] + 0.25);
        colD[r] = (int)(pcv[r] + 0.25);
    }

    double4v acc0[4] = {{0.,0.,0.,0.},{0.,0.,0.,0.},{0.,0.,0.,0.},{0.,0.,0.,0.}};
    double4v acc1[4] = {{0.,0.,0.,0.},{0.,0.,0.,0.},{0.,0.,0.,0.},{0.,0.,0.,0.}};

    const int    kbase = wq * (DD / 4);  // 512 k per quarter
    const float* wb0   = Wl + (size_t)(n0 + c) * DD + kbase + 4 * q;
    const float* wb1   = wb0 + (size_t)16 * DD;
    const int*   ibase = idx ? (idx + kbase + 4 * q) : nullptr;

    float4 wv0[4], wv1[4];   // W pipelines (2 n-rows), static slots
    float4 sv[4];            // src pipeline, static slots
    int4   iv[4];            // idx pipeline, static slots

    // ---- prologue: groups 0..3 ----
    #pragma unroll
    for (int p = 0; p < 4; ++p) {
        wv0[p] = *(const float4*)(wb0 + 16 * p);
        wv1[p] = *(const float4*)(wb1 + 16 * p);
    }
    #pragma unroll
    for (int p = 0; p < 4; ++p) {
        int r0, r1, r2, r3;
        if (ibase) {
            int4 iv0 = *(const int4*)(ibase + 16 * p);
            r0 = iv0.x; r1 = iv0.y; r2 = iv0.z; r3 = iv0.w;
        } else {
            int kb = kbase + 16 * p + 4 * q;
            r0 = kb; r1 = kb + 1; r2 = kb + 2; r3 = kb + 3;
        }
        sv[p].x = srcT[(size_t)r0 * BB + bcol];
        sv[p].y = srcT[(size_t)r1 * BB + bcol];
        sv[p].z = srcT[(size_t)r2 * BB + bcol];
        sv[p].w = srcT[(size_t)r3 * BB + bcol];
    }
    if (ibase) {
        #pragma unroll
        for (int p = 0; p < 4; ++p) iv[p] = *(const int4*)(ibase + 16 * (4 + p));
    }

    // ---- barrier-free K-loop: 8 iterations x 4 static-slot groups ----
    for (int u = 0; u < JBQ / 4; ++u) {
        #pragma unroll
        for (int gg = 0; gg < 4; ++gg) {
            float4 w0 = wv0[gg];
            float4 w1 = wv1[gg];
            float4 s  = sv[gg];

            int jn = 4 * u + 4 + gg; if (jn > JBQ - 1) jn = JBQ - 1;
            wv0[gg] = *(const float4*)(wb0 + 16 * jn);
            wv1[gg] = *(const float4*)(wb1 + 16 * jn);

            int r0, r1, r2, r3;
            if (ibase) {
                int4 ivv = iv[gg];
                r0 = ivv.x; r1 = ivv.y; r2 = ivv.z; r3 = ivv.w;
            } else {
                int kb = kbase + 16 * jn + 4 * q;
                r0 = kb; r1 = kb + 1; r2 = kb + 2; r3 = kb + 3;
            }
            sv[gg].x = srcT[(size_t)r0 * BB + bcol];
            sv[gg].y = srcT[(size_t)r1 * BB + bcol];
            sv[gg].z = srcT[(size_t)r2 * BB + bcol];
            sv[gg].w = srcT[(size_t)r3 * BB + bcol];

            if (ibase) {
                int jm = 4 * u + 8 + gg; if (jm > JBQ - 1) jm = JBQ - 1;
                iv[gg] = *(const int4*)(ibase + 16 * jm);
            }

            acc0[0] = __builtin_amdgcn_mfma_f64_16x16x4f64((double)w0.x, (double)s.x, acc0[0], 0, 0, 0);
            acc1[0] = __builtin_amdgcn_mfma_f64_16x16x4f64((double)w1.x, (double)s.x, acc1[0], 0, 0, 0);
            acc0[1] = __builtin_amdgcn_mfma_f64_16x16x4f64((double)w0.y, (double)s.y, acc0[1], 0, 0, 0);
            acc1[1] = __builtin_amdgcn_mfma_f64_16x16x4f64((double)w1.y, (double)s.y, acc1[1], 0, 0, 0);
            acc0[2] = __builtin_amdgcn_mfma_f64_16x16x4f64((double)w0.z, (double)s.z, acc0[2], 0, 0, 0);
            acc1[2] = __builtin_amdgcn_mfma_f64_16x16x4f64((double)w1.z, (double)s.z, acc1[2], 0, 0, 0);
            acc0[3] = __builtin_amdgcn_mfma_f64_16x16x4f64((double)w0.w, (double)s.w, acc0[3], 0, 0, 0);
            acc1[3] = __builtin_amdgcn_mfma_f64_16x16x4f64((double)w1.w, (double)s.w, acc1[3], 0, 0, 0);
        }
    }

    double4v a0 = (acc0[0] + acc0[1]) + (acc0[2] + acc0[3]);
    double4v a1 = (acc1[0] + acc1[1]) + (acc1[2] + acc1[3]);

    {
        double* my = red + ((size_t)wq * 64 + lane) * 8;
        #pragma unroll
        for (int r = 0; r < 4; ++r) { my[r] = a0[r]; my[4 + r] = a1[r]; }
    }
    __syncthreads();
    if (wq < 2) {
        const int off = wq * 4;
        double a[4];
        #pragma unroll
        for (int r = 0; r < 4; ++r) {
            a[r] =  red[((size_t)0 * 64 + lane) * 8 + off + r];
            a[r] += red[((size_t)1 * 64 + lane) * 8 + off + r];
            a[r] += red[((size_t)2 * 64 + lane) * 8 + off + r];
            a[r] += red[((size_t)3 * 64 + lane) * 8 + off + r];
        }

        const double th = (double)thresholds[l];
        const int T = *Tptr;
        const float sc = isLast ? 1.0f : (1.0f / (float)T);
        double m0 = 0., m1 = 0., m2 = 0., m3 = 0.;
        int c0 = 0, c1 = 0, c2 = 0, c3 = 0;
        for (int tt = 0; tt < T; ++tt) {
            m0 += a[0]; if (m0 > th) { c0++; m0 -= th; }
            m1 += a[1]; if (m1 > th) { c1++; m1 -= th; }
            m2 += a[2]; if (m2 > th) { c2++; m2 -= th; }
            m3 += a[3]; if (m3 > th) { c3++; m3 -= th; }
        }
        int cnt[4] = {c0, c1, c2, c3};
        #pragma unroll
        for (int r = 0; r < 4; ++r) {
            int n = n0 + 16 * wq + rowD[r];
            int b = btile * 16 + colD[r];
            dst[(size_t)n * BB + b] = (float)cnt[r] * sc;
            if (c8T) c8T[(size_t)b * NN + n] = (signed char)cnt[r];
        }
    }
}

// ---------------------------------------------------------------------------
// Integer-exact layer kernel (layers 1..3), sign-safe base-128 digits:
//   sum_k W*cnt = 2^-48 * sum_j 128^j * acc_j  -  0.5 * acc_ones
// acc_j  = i32 dot of digit plane j (u8 in [0,127]) with counts (0..64),
// acc_ones = column sums of counts via a constant all-ones A plane.
// All accs exact in i32 (per-quarter: 127*64*512 < 2^23).
// D-layout discovered with i8-NATIVE probes (f64 probe layout is NOT verified
// to match i32 -- that was the R1/R2 bug hypothesis). Row probe: A bytes all
// = c (row label), B one-hot => D[i][j] = rowlabel(i). Col probe swapped.
// ---------------------------------------------------------------------------
__global__ __launch_bounds__(256, 2) void layer_i8_kernel(
    const signed char* __restrict__ B8,    // g8T [BB][DD] i8 counts (gathered)
    const signed char* __restrict__ Wd7,   // 7 digit planes [j][n][k], stride DP
    const float* __restrict__ thresholds, int l,
    const int*   __restrict__ Tptr,
    float* __restrict__ dst, signed char* __restrict__ c8T, int isLast)
{
    __shared__ double red[4 * 64 * 8];

    const int t    = threadIdx.x;
    const int wq   = t >> 6;
    const int lane = t & 63;
    const int q    = lane >> 4;
    const int c    = lane & 15;

    const int g     = blockIdx.x;
    const int btile = (g >> 3) & 7;
    const int nsup  = (g & 7) | ((g >> 6) << 3);
    const int n0    = nsup * 32;
    const int bcol  = btile * 16 + c;

    // ---- i8-native D-layout probe (no layout assumptions) ----
    int rowD[4], colD[4];
    {
        const int cb  = c * 0x01010101;     // every byte = c (label 0..15)
        const int hot = (q == 0) ? 1 : 0;   // single byte = 1 on q==0 lanes
        int4v aLab = {cb, cb, cb, cb};
        int4v oneh = {hot, 0, 0, 0};
        int4v dR = {0, 0, 0, 0}, dC = {0, 0, 0, 0};
        dR = __builtin_amdgcn_mfma_i32_16x16x64_i8(aLab, oneh, dR, 0, 0, 0);
        dC = __builtin_amdgcn_mfma_i32_16x16x64_i8(oneh, aLab, dC, 0, 0, 0);
        #pragma unroll
        for (int r = 0; r < 4; ++r) { rowD[r] = dR[r]; colD[r] = dC[r]; }
    }

    int4v acc0[NDIG], acc1[NDIG], accS = (int4v)0;
    #pragma unroll
    for (int j = 0; j < NDIG; ++j) { acc0[j] = (int4v)0; acc1[j] = (int4v)0; }

    const size_t DP = (size_t)NN * DD;
    const int kbase = wq * (DD / 4);     // 512 k per quarter
    const signed char* ap0 = Wd7 + (size_t)(n0 + c) * DD + kbase + 16 * q;
    const signed char* ap1 = ap0 + (size_t)16 * DD;
    const signed char* bp  = B8  + (size_t)bcol * DD + kbase + 16 * q;

    const int4v ones = {0x01010101, 0x01010101, 0x01010101, 0x01010101};

    #pragma unroll
    for (int kc = 0; kc < 8; ++kc) {
        const int off = kc * 64;
        int4v bfv = *(const int4v*)(bp + off);
        int4v a0[NDIG], a1[NDIG];
        #pragma unroll
        for (int j = 0; j < NDIG; ++j) {
            a0[j] = *(const int4v*)(ap0 + (size_t)j * DP + off);
            a1[j] = *(const int4v*)(ap1 + (size_t)j * DP + off);
        }
        #pragma unroll
        for (int j = 0; j < NDIG; ++j) {
            acc0[j] = __builtin_amdgcn_mfma_i32_16x16x64_i8(a0[j], bfv, acc0[j], 0, 0, 0);
            acc1[j] = __builtin_amdgcn_mfma_i32_16x16x64_i8(a1[j], bfv, acc1[j], 0, 0, 0);
        }
        accS = __builtin_amdgcn_mfma_i32_16x16x64_i8(ones, bfv, accS, 0, 0, 0);
    }

    // digit recombination (per-quarter, exact powers of two; bias removed here)
    const double S0 = 0x1p-48, S1 = 0x1p-41, S2 = 0x1p-34, S3 = 0x1p-27,
                 S4 = 0x1p-20, S5 = 0x1p-13, S6 = 0x1p-6;
    {
        double* my = red + ((size_t)wq * 64 + lane) * 8;
        #pragma unroll
        for (int r = 0; r < 4; ++r) {
            double corr = 0.5 * (double)accS[r];
            my[r]     = S0 * (double)acc0[0][r] + S1 * (double)acc0[1][r]
                      + S2 * (double)acc0[2][r] + S3 * (double)acc0[3][r]
                      + S4 * (double)acc0[4][r] + S5 * (double)acc0[5][r]
                      + S6 * (double)acc0[6][r] - corr;
            my[4 + r] = S0 * (double)acc1[0][r] + S1 * (double)acc1[1][r]
                      + S2 * (double)acc1[2][r] + S3 * (double)acc1[3][r]
                      + S4 * (double)acc1[4][r] + S5 * (double)acc1[5][r]
                      + S6 * (double)acc1[6][r] - corr;
        }
    }
    __syncthreads();
    if (wq < 2) {
        const int off = wq * 4;
        double a[4];
        #pragma unroll
        for (int r = 0; r < 4; ++r) {
            a[r] =  red[((size_t)0 * 64 + lane) * 8 + off + r];
            a[r] += red[((size_t)1 * 64 + lane) * 8 + off + r];
            a[r] += red[((size_t)2 * 64 + lane) * 8 + off + r];
            a[r] += red[((size_t)3 * 64 + lane) * 8 + off + r];
        }

        const double th = (double)thresholds[l];
        const int T = *Tptr;
        const double invT = 1.0 / (double)T;
        const float sc = isLast ? 1.0f : (1.0f / (float)T);
        double m0 = 0., m1 = 0., m2 = 0., m3 = 0.;
        int c0 = 0, c1 = 0, c2 = 0, c3 = 0;
        const double v0 = a[0] * invT, v1 = a[1] * invT,
                     v2 = a[2] * invT, v3 = a[3] * invT;
        for (int tt = 0; tt < T; ++tt) {
            m0 += v0; if (m0 > th) { c0++; m0 -= th; }
            m1 += v1; if (m1 > th) { c1++; m1 -= th; }
            m2 += v2; if (m2 > th) { c2++; m2 -= th; }
            m3 += v3; if (m3 > th) { c3++; m3 -= th; }
        }
        int cnt[4] = {c0, c1, c2, c3};
        #pragma unroll
        for (int r = 0; r < 4; ++r) {
            int n = n0 + 16 * wq + rowD[r];
            int b = btile * 16 + colD[r];
            dst[(size_t)n * BB + b] = (float)cnt[r] * sc;
            if (c8T) c8T[(size_t)b * NN + n] = (signed char)cnt[r];
        }
    }
}

// ---------------------------------------------------------------------------
// Output gather: out[b, o] = cntT[out_idx[o]][b]
// ---------------------------------------------------------------------------
__global__ __launch_bounds__(256) void out_kernel(
    const float* __restrict__ cntT, const int* __restrict__ out_idx,
    float* __restrict__ out)
{
    int i = blockIdx.x * 256 + threadIdx.x;   // over BB*OUTN
    int b = i >> 10;
    int o = i & 1023;
    out[i] = cntT[(size_t)out_idx[o] * BB + b];
}

extern "C" void kernel_launch(void* const* d_in, const int* in_sizes, int n_in,
                              void* d_out, int out_size, void* d_ws, size_t ws_size,
                              hipStream_t stream)
{
    const float* x    = (const float*)d_in[0];
    const float* W    = (const float*)d_in[1];
    const float* thr  = (const float*)d_in[2];
    const int*   axon = (const int*)d_in[3];
    const int*   oidx = (const int*)d_in[4];
    const int*   Tptr = (const int*)d_in[5];
    float* out = (float*)d_out;

    const size_t DP = (size_t)NN * DD;
    char* ws = (char*)d_ws;
    float* At   = (float*)ws;                         // 1 MB [2048][128]
    float* mA   = (float*)(ws + (1u << 20));          // 1 MB ping
    float* mB   = (float*)(ws + (2u << 20));          // 1 MB pong
    float* cntT = (float*)(ws + (3u << 20));          // 1 MB
    signed char* c8A = (signed char*)(ws + (4u << 20));               // 256 KB [b][n]
    signed char* c8B = (signed char*)(ws + (4u << 20) + (256u << 10));// 256 KB
    signed char* g8T = (signed char*)(ws + (4u << 20) + (512u << 10));// 256 KB [b][k]
    signed char* Wd  = (signed char*)(ws + (5u << 20));               // 28 MB (rotating)

    const int useI8 = (ws_size >= ((size_t)34 << 20)) ? 1 : 0;

    gather0_kernel<<<(DD * BB) / 256, 256, 0, stream>>>(x, axon, At);

    if (!useI8) {
        // fallback: proven all-fp64 path (round-0 structure)
        const float* srcs[LL] = { At, mA, mB, mA };
        float*       dsts[LL] = { mA, mB, mA, cntT };
        for (int l = 0; l < LL; ++l) {
            const int* idx = (l == 0) ? nullptr : (axon + (size_t)l * DD);
            layer_kernel<<<512, 256, 0, stream>>>(
                srcs[l], idx, W + (size_t)l * NN * DD, thr, l, Tptr,
                dsts[l], nullptr, (l == LL - 1) ? 1 : 0);
        }
    } else {
        // layer 0: fp64 MFMA path (fp32 x input), emits i8 counts to c8A
        layer_kernel<<<512, 256, 0, stream>>>(
            At, nullptr, W, thr, 0, Tptr, mA, c8A, 0);

        // layers 1..3: sign-safe integer path, rotating digit buffer
        signed char* c8s[3] = { c8A, c8B, c8A };
        signed char* c8d[3] = { c8B, c8A, nullptr };
        float*       fds[3] = { mB, mA, cntT };
        for (int l = 1; l < LL; ++l) {
            wdig7_kernel<<<(int)(DP / 4) / 256, 256, 0, stream>>>(
                W + (size_t)l * DP, Wd);
            gather8_kernel<<<(BB * DD) / 256, 256, 0, stream>>>(
                c8s[l - 1], axon + (size_t)l * DD, g8T);
            layer_i8_kernel<<<512, 256, 0, stream>>>(
                g8T, Wd, thr, l, Tptr, fds[l - 1], c8d[l - 1],
                (l == LL - 1) ? 1 : 0);
        }
    }

    out_kernel<<<(BB * OUTN) / 256, 256, 0, stream>>>(cntT, oidx, out);
}

// Round 4
// 221.040 us; speedup vs baseline: 1.2107x; 1.2107x over previous
//
#include <hip/hip_runtime.h>

// Problem constants
#define BB   128
#define DD   2048
#define NN   2048
#define LL   4
#define OUTN 1024
#define JBQ  32                // 16-k groups per K-quarter (512 k / quarter)
#define NDIG 5                 // base-128 digit planes (bias 2^34, scale 2^-33)

typedef double double4v __attribute__((ext_vector_type(4)));
typedef int    int4v    __attribute__((ext_vector_type(4)));
typedef char   char4v   __attribute__((ext_vector_type(4)));

// ---------------------------------------------------------------------------
// Layer-0 transpose-gather: At[k][b] = x[b, axon_idx0[k]]
// ---------------------------------------------------------------------------
__global__ __launch_bounds__(256) void gather0_kernel(
    const float* __restrict__ x, const int* __restrict__ idx0,
    float* __restrict__ At)
{
    int i = blockIdx.x * 256 + threadIdx.x;   // over DD*BB
    int k = i >> 7;
    int b = i & 127;
    At[i] = x[b * DD + idx0[k]];
}

// ---------------------------------------------------------------------------
// W digitization, layers 1..3 in ONE launch: W fp32 -> 5 non-negative
// base-128 digit planes of V' = rint(W * 2^33) + 2^34  (V' in [0,2^35),
// valid for |W| < 2; digits in [0,127] -> sign-safe for i8 MFMA).
// TILED output layout (sector-coalesced MFMA fragment loads):
//   Wd[l][j][nsup:64][kc:32][cc:32][kk:64]   (2 KB tiles)
// addr = l*5*DP + j*DP + (n>>5)*65536 + (k>>6)*2048 + (n&31)*64 + (k&63)
// ---------------------------------------------------------------------------
__global__ __launch_bounds__(256) void wdig5_kernel(
    const float* __restrict__ W1, signed char* __restrict__ Wd)
{
    const size_t DP = (size_t)NN * DD;
    size_t i  = (size_t)blockIdx.x * 256 + threadIdx.x;   // over 3*DP/4
    int    l  = (int)(i / (DP / 4));
    size_t e4 = i - (size_t)l * (DP / 4);
    int n = (int)(e4 >> 9);
    int k = (int)(e4 & 511) * 4;
    float4 w = *(const float4*)(W1 + (size_t)l * DP + (size_t)n * DD + k);
    const float wv[4] = {w.x, w.y, w.z, w.w};
    unsigned long long V[4];
    #pragma unroll
    for (int e = 0; e < 4; ++e)
        V[e] = (unsigned long long)(__double2ll_rn((double)wv[e] * 0x1p33)
                                    + (1LL << 34));
    signed char* base = Wd + (size_t)l * 5 * DP
                      + (size_t)(n >> 5) * 65536 + (size_t)(k >> 6) * 2048
                      + (n & 31) * 64 + (k & 63);
    #pragma unroll
    for (int j = 0; j < NDIG; ++j) {
        char4v p = { (char)((V[0] >> (7 * j)) & 127),
                     (char)((V[1] >> (7 * j)) & 127),
                     (char)((V[2] >> (7 * j)) & 127),
                     (char)((V[3] >> (7 * j)) & 127) };
        *(char4v*)(base + (size_t)j * DP) = p;
    }
}

// ---------------------------------------------------------------------------
// Per-layer spike gather (layers 1..3), char4-vectorized, TILED output:
//   g8T[kc:32][b:128][kk:64]  with g8T[..] = c8T[b][idx[k]]
// ---------------------------------------------------------------------------
__global__ __launch_bounds__(256) void gather8_kernel(
    const signed char* __restrict__ c8T, const int* __restrict__ idx,
    signed char* __restrict__ g8T)
{
    int i = blockIdx.x * 256 + threadIdx.x;   // over BB*DD/4
    int b = i >> 9;
    int k = (i & 511) * 4;
    int4 id = *(const int4*)(idx + k);
    const signed char* row = c8T + (size_t)b * DD;
    char4v v = { row[id.x], row[id.y], row[id.z], row[id.w] };
    *(char4v*)(g8T + (size_t)(k >> 6) * 8192 + b * 64 + (k & 63)) = v;
}

// ---------------------------------------------------------------------------
// Barrier-free fused layer kernel, fp64 MFMA path (layer 0 / fallback).
// Proven structure; optional i8 count emission (c8T[b][n]) for the i8 path.
// ---------------------------------------------------------------------------
__global__ __launch_bounds__(256, 2) void layer_kernel(
    const float* __restrict__ srcT,   // [2048 rows][BB] fp32
    const int*   __restrict__ idx,    // nullptr => identity rows
    const float* __restrict__ Wl,     // [n][k] row-major
    const float* __restrict__ thresholds, int l,
    const int*   __restrict__ Tptr,
    float* __restrict__ dst, signed char* __restrict__ c8T, int isLast)
{
    __shared__ double red[4 * 64 * 8];   // 16 KB, epilogue only

    const int t    = threadIdx.x;
    const int wq   = t >> 6;             // K-quarter 0..3
    const int lane = t & 63;
    const int q    = lane >> 4;
    const int c    = lane & 15;

    const int g     = blockIdx.x;        // 0..511
    const int btile = (g >> 3) & 7;      // b-replicas of one nsup: same XCD (mod 8)
    const int nsup  = (g & 7) | ((g >> 6) << 3);
    const int n0    = nsup * 32;
    const int bcol  = btile * 16 + c;

    // ---- runtime D-layout probe (layout-agnostic epilogue), f64-native ----
    double4v pr = {0., 0., 0., 0.}, pcv = {0., 0., 0., 0.};
    pr  = __builtin_amdgcn_mfma_f64_16x16x4f64(0.25 * (double)c, 1.0, pr, 0, 0, 0);
    pcv = __builtin_amdgcn_mfma_f64_16x16x4f64(0.25, (double)c, pcv, 0, 0, 0);
    int rowD[4], colD[4];
    #pragma unroll
    for (int r = 0; r < 4; ++r) {
        rowD[r] = (int)(pr[r] + 0.25);
        colD[r] = (int)(pcv[r] + 0.25);
    }

    double4v acc0[4] = {{0.,0.,0.,0.},{0.,0.,0.,0.},{0.,0.,0.,0.},{0.,0.,0.,0.}};
    double4v acc1[4] = {{0.,0.,0.,0.},{0.,0.,0.,0.},{0.,0.,0.,0.},{0.,0.,0.,0.}};

    const int    kbase = wq * (DD / 4);  // 512 k per quarter
    const float* wb0   = Wl + (size_t)(n0 + c) * DD + kbase + 4 * q;
    const float* wb1   = wb0 + (size_t)16 * DD;
    const int*   ibase = idx ? (idx + kbase + 4 * q) : nullptr;

    float4 wv0[4], wv1[4];   // W pipelines (2 n-rows), static slots
    float4 sv[4];            // src pipeline, static slots
    int4   iv[4];            // idx pipeline, static slots

    // ---- prologue: groups 0..3 ----
    #pragma unroll
    for (int p = 0; p < 4; ++p) {
        wv0[p] = *(const float4*)(wb0 + 16 * p);
        wv1[p] = *(const float4*)(wb1 + 16 * p);
    }
    #pragma unroll
    for (int p = 0; p < 4; ++p) {
        int r0, r1, r2, r3;
        if (ibase) {
            int4 iv0 = *(const int4*)(ibase + 16 * p);
            r0 = iv0.x; r1 = iv0.y; r2 = iv0.z; r3 = iv0.w;
        } else {
            int kb = kbase + 16 * p + 4 * q;
            r0 = kb; r1 = kb + 1; r2 = kb + 2; r3 = kb + 3;
        }
        sv[p].x = srcT[(size_t)r0 * BB + bcol];
        sv[p].y = srcT[(size_t)r1 * BB + bcol];
        sv[p].z = srcT[(size_t)r2 * BB + bcol];
        sv[p].w = srcT[(size_t)r3 * BB + bcol];
    }
    if (ibase) {
        #pragma unroll
        for (int p = 0; p < 4; ++p) iv[p] = *(const int4*)(ibase + 16 * (4 + p));
    }

    // ---- barrier-free K-loop: 8 iterations x 4 static-slot groups ----
    for (int u = 0; u < JBQ / 4; ++u) {
        #pragma unroll
        for (int gg = 0; gg < 4; ++gg) {
            float4 w0 = wv0[gg];
            float4 w1 = wv1[gg];
            float4 s  = sv[gg];

            int jn = 4 * u + 4 + gg; if (jn > JBQ - 1) jn = JBQ - 1;
            wv0[gg] = *(const float4*)(wb0 + 16 * jn);
            wv1[gg] = *(const float4*)(wb1 + 16 * jn);

            int r0, r1, r2, r3;
            if (ibase) {
                int4 ivv = iv[gg];
                r0 = ivv.x; r1 = ivv.y; r2 = ivv.z; r3 = ivv.w;
            } else {
                int kb = kbase + 16 * jn + 4 * q;
                r0 = kb; r1 = kb + 1; r2 = kb + 2; r3 = kb + 3;
            }
            sv[gg].x = srcT[(size_t)r0 * BB + bcol];
            sv[gg].y = srcT[(size_t)r1 * BB + bcol];
            sv[gg].z = srcT[(size_t)r2 * BB + bcol];
            sv[gg].w = srcT[(size_t)r3 * BB + bcol];

            if (ibase) {
                int jm = 4 * u + 8 + gg; if (jm > JBQ - 1) jm = JBQ - 1;
                iv[gg] = *(const int4*)(ibase + 16 * jm);
            }

            acc0[0] = __builtin_amdgcn_mfma_f64_16x16x4f64((double)w0.x, (double)s.x, acc0[0], 0, 0, 0);
            acc1[0] = __builtin_amdgcn_mfma_f64_16x16x4f64((double)w1.x, (double)s.x, acc1[0], 0, 0, 0);
            acc0[1] = __builtin_amdgcn_mfma_f64_16x16x4f64((double)w0.y, (double)s.y, acc0[1], 0, 0, 0);
            acc1[1] = __builtin_amdgcn_mfma_f64_16x16x4f64((double)w1.y, (double)s.y, acc1[1], 0, 0, 0);
            acc0[2] = __builtin_amdgcn_mfma_f64_16x16x4f64((double)w0.z, (double)s.z, acc0[2], 0, 0, 0);
            acc1[2] = __builtin_amdgcn_mfma_f64_16x16x4f64((double)w1.z, (double)s.z, acc1[2], 0, 0, 0);
            acc0[3] = __builtin_amdgcn_mfma_f64_16x16x4f64((double)w0.w, (double)s.w, acc0[3], 0, 0, 0);
            acc1[3] = __builtin_amdgcn_mfma_f64_16x16x4f64((double)w1.w, (double)s.w, acc1[3], 0, 0, 0);
        }
    }

    double4v a0 = (acc0[0] + acc0[1]) + (acc0[2] + acc0[3]);
    double4v a1 = (acc1[0] + acc1[1]) + (acc1[2] + acc1[3]);

    {
        double* my = red + ((size_t)wq * 64 + lane) * 8;
        #pragma unroll
        for (int r = 0; r < 4; ++r) { my[r] = a0[r]; my[4 + r] = a1[r]; }
    }
    __syncthreads();
    if (wq < 2) {
        const int off = wq * 4;
        double a[4];
        #pragma unroll
        for (int r = 0; r < 4; ++r) {
            a[r] =  red[((size_t)0 * 64 + lane) * 8 + off + r];
            a[r] += red[((size_t)1 * 64 + lane) * 8 + off + r];
            a[r] += red[((size_t)2 * 64 + lane) * 8 + off + r];
            a[r] += red[((size_t)3 * 64 + lane) * 8 + off + r];
        }

        const double th = (double)thresholds[l];
        const int T = *Tptr;
        const float sc = isLast ? 1.0f : (1.0f / (float)T);
        double m0 = 0., m1 = 0., m2 = 0., m3 = 0.;
        int c0 = 0, c1 = 0, c2 = 0, c3 = 0;
        for (int tt = 0; tt < T; ++tt) {
            m0 += a[0]; if (m0 > th) { c0++; m0 -= th; }
            m1 += a[1]; if (m1 > th) { c1++; m1 -= th; }
            m2 += a[2]; if (m2 > th) { c2++; m2 -= th; }
            m3 += a[3]; if (m3 > th) { c3++; m3 -= th; }
        }
        int cnt[4] = {c0, c1, c2, c3};
        #pragma unroll
        for (int r = 0; r < 4; ++r) {
            int n = n0 + 16 * wq + rowD[r];
            int b = btile * 16 + colD[r];
            dst[(size_t)n * BB + b] = (float)cnt[r] * sc;
            if (c8T) c8T[(size_t)b * NN + n] = (signed char)cnt[r];
        }
    }
}

// ---------------------------------------------------------------------------
// Integer-exact layer kernel (layers 1..3), base-128 digits, TILED operands:
//   sum_k W*cnt = sum_j 2^(7j-33) * acc_j  -  2.0 * acc_ones
// A tiles: Wd[j][nsup][ck][cc:32][kk:64] -> lane (q,c) reads c*64+q*16
// (+1024 for n-tile 1): fully coalesced 1KB/instr.  B tiles: g8T[ck][b][kk]
// -> bcol*64+q*16: coalesced.  All accs exact in i32 (127*64*512 < 2^23).
// D-layout via i8-NATIVE probes (R3-proven: i32 D-layout != f64 D-layout).
// ---------------------------------------------------------------------------
__global__ __launch_bounds__(256, 2) void layer_i8_kernel(
    const signed char* __restrict__ B8,    // g8T tiled [ck:32][b:128][kk:64]
    const signed char* __restrict__ Wd5,   // 5 tiled digit planes, stride DP
    const float* __restrict__ thresholds, int l,
    const int*   __restrict__ Tptr,
    float* __restrict__ dst, signed char* __restrict__ c8T, int isLast)
{
    __shared__ double red[4 * 64 * 8];

    const int t    = threadIdx.x;
    const int wq   = t >> 6;
    const int lane = t & 63;
    const int q    = lane >> 4;
    const int c    = lane & 15;

    const int g     = blockIdx.x;
    const int btile = (g >> 3) & 7;
    const int nsup  = (g & 7) | ((g >> 6) << 3);
    const int n0    = nsup * 32;
    const int bcol  = btile * 16 + c;

    // ---- i8-native D-layout probe (R3-proven) ----
    int rowD[4], colD[4];
    {
        const int cb  = c * 0x01010101;     // every byte = c (label 0..15)
        const int hot = (q == 0) ? 1 : 0;   // single byte = 1 on q==0 lanes
        int4v aLab = {cb, cb, cb, cb};
        int4v oneh = {hot, 0, 0, 0};
        int4v dR = {0, 0, 0, 0}, dC = {0, 0, 0, 0};
        dR = __builtin_amdgcn_mfma_i32_16x16x64_i8(aLab, oneh, dR, 0, 0, 0);
        dC = __builtin_amdgcn_mfma_i32_16x16x64_i8(oneh, aLab, dC, 0, 0, 0);
        #pragma unroll
        for (int r = 0; r < 4; ++r) { rowD[r] = dR[r]; colD[r] = dC[r]; }
    }

    int4v acc0[NDIG], acc1[NDIG], accS = (int4v)0;
    #pragma unroll
    for (int j = 0; j < NDIG; ++j) { acc0[j] = (int4v)0; acc1[j] = (int4v)0; }

    const size_t DP = (size_t)NN * DD;
    // tiled bases: A fragment for lane (q,c) at tile offset c*64+q*16
    const signed char* ab = Wd5 + (size_t)nsup * 65536 + c * 64 + q * 16;
    const signed char* bb = B8 + bcol * 64 + q * 16;

    const int4v ones = {0x01010101, 0x01010101, 0x01010101, 0x01010101};

    #pragma unroll
    for (int kc = 0; kc < 8; ++kc) {
        const int ck = wq * 8 + kc;          // global 64-k chunk 0..31
        int4v bfv = *(const int4v*)(bb + (size_t)ck * 8192);
        int4v a0[NDIG], a1[NDIG];
        #pragma unroll
        for (int j = 0; j < NDIG; ++j) {
            const signed char* ap = ab + (size_t)j * DP + (size_t)ck * 2048;
            a0[j] = *(const int4v*)ap;
            a1[j] = *(const int4v*)(ap + 1024);
        }
        #pragma unroll
        for (int j = 0; j < NDIG; ++j) {
            acc0[j] = __builtin_amdgcn_mfma_i32_16x16x64_i8(a0[j], bfv, acc0[j], 0, 0, 0);
            acc1[j] = __builtin_amdgcn_mfma_i32_16x16x64_i8(a1[j], bfv, acc1[j], 0, 0, 0);
        }
        accS = __builtin_amdgcn_mfma_i32_16x16x64_i8(ones, bfv, accS, 0, 0, 0);
    }

    // digit recombination: exact powers of two; bias 2^34 removed via accS
    const double S0 = 0x1p-33, S1 = 0x1p-26, S2 = 0x1p-19,
                 S3 = 0x1p-12, S4 = 0x1p-5;
    {
        double* my = red + ((size_t)wq * 64 + lane) * 8;
        #pragma unroll
        for (int r = 0; r < 4; ++r) {
            double corr = 2.0 * (double)accS[r];
            my[r]     = S0 * (double)acc0[0][r] + S1 * (double)acc0[1][r]
                      + S2 * (double)acc0[2][r] + S3 * (double)acc0[3][r]
                      + S4 * (double)acc0[4][r] - corr;
            my[4 + r] = S0 * (double)acc1[0][r] + S1 * (double)acc1[1][r]
                      + S2 * (double)acc1[2][r] + S3 * (double)acc1[3][r]
                      + S4 * (double)acc1[4][r] - corr;
        }
    }
    __syncthreads();
    if (wq < 2) {
        const int off = wq * 4;
        double a[4];
        #pragma unroll
        for (int r = 0; r < 4; ++r) {
            a[r] =  red[((size_t)0 * 64 + lane) * 8 + off + r];
            a[r] += red[((size_t)1 * 64 + lane) * 8 + off + r];
            a[r] += red[((size_t)2 * 64 + lane) * 8 + off + r];
            a[r] += red[((size_t)3 * 64 + lane) * 8 + off + r];
        }

        const double th = (double)thresholds[l];
        const int T = *Tptr;
        const double invT = 1.0 / (double)T;
        const float sc = isLast ? 1.0f : (1.0f / (float)T);
        double m0 = 0., m1 = 0., m2 = 0., m3 = 0.;
        int c0 = 0, c1 = 0, c2 = 0, c3 = 0;
        const double v0 = a[0] * invT, v1 = a[1] * invT,
                     v2 = a[2] * invT, v3 = a[3] * invT;
        for (int tt = 0; tt < T; ++tt) {
            m0 += v0; if (m0 > th) { c0++; m0 -= th; }
            m1 += v1; if (m1 > th) { c1++; m1 -= th; }
            m2 += v2; if (m2 > th) { c2++; m2 -= th; }
            m3 += v3; if (m3 > th) { c3++; m3 -= th; }
        }
        int cnt[4] = {c0, c1, c2, c3};
        #pragma unroll
        for (int r = 0; r < 4; ++r) {
            int n = n0 + 16 * wq + rowD[r];
            int b = btile * 16 + colD[r];
            dst[(size_t)n * BB + b] = (float)cnt[r] * sc;
            if (c8T) c8T[(size_t)b * NN + n] = (signed char)cnt[r];
        }
    }
}

// ---------------------------------------------------------------------------
// Output gather: out[b, o] = cntT[out_idx[o]][b]
// ---------------------------------------------------------------------------
__global__ __launch_bounds__(256) void out_kernel(
    const float* __restrict__ cntT, const int* __restrict__ out_idx,
    float* __restrict__ out)
{
    int i = blockIdx.x * 256 + threadIdx.x;   // over BB*OUTN
    int b = i >> 10;
    int o = i & 1023;
    out[i] = cntT[(size_t)out_idx[o] * BB + b];
}

extern "C" void kernel_launch(void* const* d_in, const int* in_sizes, int n_in,
                              void* d_out, int out_size, void* d_ws, size_t ws_size,
                              hipStream_t stream)
{
    const float* x    = (const float*)d_in[0];
    const float* W    = (const float*)d_in[1];
    const float* thr  = (const float*)d_in[2];
    const int*   axon = (const int*)d_in[3];
    const int*   oidx = (const int*)d_in[4];
    const int*   Tptr = (const int*)d_in[5];
    float* out = (float*)d_out;

    const size_t DP = (size_t)NN * DD;
    char* ws = (char*)d_ws;
    float* At   = (float*)ws;                         // 1 MB [2048][128]
    float* mA   = (float*)(ws + (1u << 20));          // 1 MB ping
    float* mB   = (float*)(ws + (2u << 20));          // 1 MB pong
    float* cntT = (float*)(ws + (3u << 20));          // 1 MB
    signed char* c8A = (signed char*)(ws + (4u << 20));               // 256 KB [b][n]
    signed char* c8B = (signed char*)(ws + (4u << 20) + (256u << 10));// 256 KB
    signed char* g8T = (signed char*)(ws + (4u << 20) + (512u << 10));// 256 KB tiled
    signed char* Wd  = (signed char*)(ws + (5u << 20));               // 60 MB (3 layers x 5 planes)

    const int useI8 = (ws_size >= ((size_t)80 << 20)) ? 1 : 0;

    gather0_kernel<<<(DD * BB) / 256, 256, 0, stream>>>(x, axon, At);

    if (!useI8) {
        // fallback: proven all-fp64 path (round-0 structure)
        const float* srcs[LL] = { At, mA, mB, mA };
        float*       dsts[LL] = { mA, mB, mA, cntT };
        for (int l = 0; l < LL; ++l) {
            const int* idx = (l == 0) ? nullptr : (axon + (size_t)l * DD);
            layer_kernel<<<512, 256, 0, stream>>>(
                srcs[l], idx, W + (size_t)l * NN * DD, thr, l, Tptr,
                dsts[l], nullptr, (l == LL - 1) ? 1 : 0);
        }
    } else {
        // digitize W for layers 1..3 (one launch, tiled planes)
        wdig5_kernel<<<(int)(3 * (DP / 4) / 256), 256, 0, stream>>>(W + DP, Wd);

        // layer 0: fp64 MFMA path (fp32 x input), emits i8 counts to c8A
        layer_kernel<<<512, 256, 0, stream>>>(
            At, nullptr, W, thr, 0, Tptr, mA, c8A, 0);

        // layers 1..3: integer path, tiled operands
        signed char* c8s[3] = { c8A, c8B, c8A };
        signed char* c8d[3] = { c8B, c8A, nullptr };
        float*       fds[3] = { mB, mA, cntT };
        for (int l = 1; l < LL; ++l) {
            gather8_kernel<<<(BB * DD / 4) / 256, 256, 0, stream>>>(
                c8s[l - 1], axon + (size_t)l * DD, g8T);
            layer_i8_kernel<<<512, 256, 0, stream>>>(
                g8T, Wd + (size_t)(l - 1) * 5 * DP, thr, l, Tptr,
                fds[l - 1], c8d[l - 1], (l == LL - 1) ? 1 : 0);
        }
    }

    out_kernel<<<(BB * OUTN) / 256, 256, 0, stream>>>(cntT, oidx, out);
}

// Round 5
// 215.404 us; speedup vs baseline: 1.2424x; 1.0262x over previous
//
#include <hip/hip_runtime.h>

// Problem constants
#define BB   128
#define DD   2048
#define NN   2048
#define LL   4
#define OUTN 1024
#define JBQ  32                // 16-k groups per K-quarter (512 k / quarter)
#define NDIG 5                 // base-128 digit planes (bias 2^34, scale 2^-33)

typedef double double4v __attribute__((ext_vector_type(4)));
typedef int    int4v    __attribute__((ext_vector_type(4)));
typedef char   char4v   __attribute__((ext_vector_type(4)));

// ---------------------------------------------------------------------------
// Layer-0 transpose-gather: At[k][b] = x[b, axon_idx0[k]]
// ---------------------------------------------------------------------------
__global__ __launch_bounds__(256) void gather0_kernel(
    const float* __restrict__ x, const int* __restrict__ idx0,
    float* __restrict__ At)
{
    int i = blockIdx.x * 256 + threadIdx.x;   // over DD*BB
    int k = i >> 7;
    int b = i & 127;
    At[i] = x[b * DD + idx0[k]];
}

// ---------------------------------------------------------------------------
// W digitization, layers 1..3 in ONE launch: W fp32 -> 5 non-negative
// base-128 digit planes of V' = rint(W * 2^33) + 2^34  (V' in [0,2^35),
// valid for |W| < 2; digits in [0,127] -> sign-safe for i8 MFMA).
// TILED output layout (sector-coalesced MFMA fragment loads):
//   Wd[l][j][nsup:64][kc:32][cc:32][kk:64]   (2 KB tiles)
// ---------------------------------------------------------------------------
__global__ __launch_bounds__(256) void wdig5_kernel(
    const float* __restrict__ W1, signed char* __restrict__ Wd)
{
    const size_t DP = (size_t)NN * DD;
    size_t i  = (size_t)blockIdx.x * 256 + threadIdx.x;   // over 3*DP/4
    int    l  = (int)(i / (DP / 4));
    size_t e4 = i - (size_t)l * (DP / 4);
    int n = (int)(e4 >> 9);
    int k = (int)(e4 & 511) * 4;
    float4 w = *(const float4*)(W1 + (size_t)l * DP + (size_t)n * DD + k);
    const float wv[4] = {w.x, w.y, w.z, w.w};
    unsigned long long V[4];
    #pragma unroll
    for (int e = 0; e < 4; ++e)
        V[e] = (unsigned long long)(__double2ll_rn((double)wv[e] * 0x1p33)
                                    + (1LL << 34));
    signed char* base = Wd + (size_t)l * 5 * DP
                      + (size_t)(n >> 5) * 65536 + (size_t)(k >> 6) * 2048
                      + (n & 31) * 64 + (k & 63);
    #pragma unroll
    for (int j = 0; j < NDIG; ++j) {
        char4v p = { (char)((V[0] >> (7 * j)) & 127),
                     (char)((V[1] >> (7 * j)) & 127),
                     (char)((V[2] >> (7 * j)) & 127),
                     (char)((V[3] >> (7 * j)) & 127) };
        *(char4v*)(base + (size_t)j * DP) = p;
    }
}

// ---------------------------------------------------------------------------
// Per-layer spike gather (layers 1..3), char4-vectorized, TILED output:
//   g8T[kc:32][b:128][kk:64]  with g8T[..] = c8T[b][idx[k]]
// ---------------------------------------------------------------------------
__global__ __launch_bounds__(256) void gather8_kernel(
    const signed char* __restrict__ c8T, const int* __restrict__ idx,
    signed char* __restrict__ g8T)
{
    int i = blockIdx.x * 256 + threadIdx.x;   // over BB*DD/4
    int b = i >> 9;
    int k = (i & 511) * 4;
    int4 id = *(const int4*)(idx + k);
    const signed char* row = c8T + (size_t)b * DD;
    char4v v = { row[id.x], row[id.y], row[id.z], row[id.w] };
    *(char4v*)(g8T + (size_t)(k >> 6) * 8192 + b * 64 + (k & 63)) = v;
}

// ---------------------------------------------------------------------------
// Barrier-free fused layer kernel, fp64 MFMA path (layer 0 / fallback).
// Proven structure; optional i8 count emission (c8T[b][n]) for the i8 path.
// ---------------------------------------------------------------------------
__global__ __launch_bounds__(256, 2) void layer_kernel(
    const float* __restrict__ srcT,   // [2048 rows][BB] fp32
    const int*   __restrict__ idx,    // nullptr => identity rows
    const float* __restrict__ Wl,     // [n][k] row-major
    const float* __restrict__ thresholds, int l,
    const int*   __restrict__ Tptr,
    float* __restrict__ dst, signed char* __restrict__ c8T, int isLast)
{
    __shared__ double red[4 * 64 * 8];   // 16 KB, epilogue only

    const int t    = threadIdx.x;
    const int wq   = t >> 6;             // K-quarter 0..3
    const int lane = t & 63;
    const int q    = lane >> 4;
    const int c    = lane & 15;

    const int g     = blockIdx.x;        // 0..511
    const int btile = (g >> 3) & 7;      // b-replicas of one nsup: same XCD (mod 8)
    const int nsup  = (g & 7) | ((g >> 6) << 3);
    const int n0    = nsup * 32;
    const int bcol  = btile * 16 + c;

    // ---- runtime D-layout probe (layout-agnostic epilogue), f64-native ----
    double4v pr = {0., 0., 0., 0.}, pcv = {0., 0., 0., 0.};
    pr  = __builtin_amdgcn_mfma_f64_16x16x4f64(0.25 * (double)c, 1.0, pr, 0, 0, 0);
    pcv = __builtin_amdgcn_mfma_f64_16x16x4f64(0.25, (double)c, pcv, 0, 0, 0);
    int rowD[4], colD[4];
    #pragma unroll
    for (int r = 0; r < 4; ++r) {
        rowD[r] = (int)(pr[r] + 0.25);
        colD[r] = (int)(pcv[r] + 0.25);
    }

    double4v acc0[4] = {{0.,0.,0.,0.},{0.,0.,0.,0.},{0.,0.,0.,0.},{0.,0.,0.,0.}};
    double4v acc1[4] = {{0.,0.,0.,0.},{0.,0.,0.,0.},{0.,0.,0.,0.},{0.,0.,0.,0.}};

    const int    kbase = wq * (DD / 4);  // 512 k per quarter
    const float* wb0   = Wl + (size_t)(n0 + c) * DD + kbase + 4 * q;
    const float* wb1   = wb0 + (size_t)16 * DD;
    const int*   ibase = idx ? (idx + kbase + 4 * q) : nullptr;

    float4 wv0[4], wv1[4];   // W pipelines (2 n-rows), static slots
    float4 sv[4];            // src pipeline, static slots
    int4   iv[4];            // idx pipeline, static slots

    // ---- prologue: groups 0..3 ----
    #pragma unroll
    for (int p = 0; p < 4; ++p) {
        wv0[p] = *(const float4*)(wb0 + 16 * p);
        wv1[p] = *(const float4*)(wb1 + 16 * p);
    }
    #pragma unroll
    for (int p = 0; p < 4; ++p) {
        int r0, r1, r2, r3;
        if (ibase) {
            int4 iv0 = *(const int4*)(ibase + 16 * p);
            r0 = iv0.x; r1 = iv0.y; r2 = iv0.z; r3 = iv0.w;
        } else {
            int kb = kbase + 16 * p + 4 * q;
            r0 = kb; r1 = kb + 1; r2 = kb + 2; r3 = kb + 3;
        }
        sv[p].x = srcT[(size_t)r0 * BB + bcol];
        sv[p].y = srcT[(size_t)r1 * BB + bcol];
        sv[p].z = srcT[(size_t)r2 * BB + bcol];
        sv[p].w = srcT[(size_t)r3 * BB + bcol];
    }
    if (ibase) {
        #pragma unroll
        for (int p = 0; p < 4; ++p) iv[p] = *(const int4*)(ibase + 16 * (4 + p));
    }

    // ---- barrier-free K-loop: 8 iterations x 4 static-slot groups ----
    for (int u = 0; u < JBQ / 4; ++u) {
        #pragma unroll
        for (int gg = 0; gg < 4; ++gg) {
            float4 w0 = wv0[gg];
            float4 w1 = wv1[gg];
            float4 s  = sv[gg];

            int jn = 4 * u + 4 + gg; if (jn > JBQ - 1) jn = JBQ - 1;
            wv0[gg] = *(const float4*)(wb0 + 16 * jn);
            wv1[gg] = *(const float4*)(wb1 + 16 * jn);

            int r0, r1, r2, r3;
            if (ibase) {
                int4 ivv = iv[gg];
                r0 = ivv.x; r1 = ivv.y; r2 = ivv.z; r3 = ivv.w;
            } else {
                int kb = kbase + 16 * jn + 4 * q;
                r0 = kb; r1 = kb + 1; r2 = kb + 2; r3 = kb + 3;
            }
            sv[gg].x = srcT[(size_t)r0 * BB + bcol];
            sv[gg].y = srcT[(size_t)r1 * BB + bcol];
            sv[gg].z = srcT[(size_t)r2 * BB + bcol];
            sv[gg].w = srcT[(size_t)r3 * BB + bcol];

            if (ibase) {
                int jm = 4 * u + 8 + gg; if (jm > JBQ - 1) jm = JBQ - 1;
                iv[gg] = *(const int4*)(ibase + 16 * jm);
            }

            acc0[0] = __builtin_amdgcn_mfma_f64_16x16x4f64((double)w0.x, (double)s.x, acc0[0], 0, 0, 0);
            acc1[0] = __builtin_amdgcn_mfma_f64_16x16x4f64((double)w1.x, (double)s.x, acc1[0], 0, 0, 0);
            acc0[1] = __builtin_amdgcn_mfma_f64_16x16x4f64((double)w0.y, (double)s.y, acc0[1], 0, 0, 0);
            acc1[1] = __builtin_amdgcn_mfma_f64_16x16x4f64((double)w1.y, (double)s.y, acc1[1], 0, 0, 0);
            acc0[2] = __builtin_amdgcn_mfma_f64_16x16x4f64((double)w0.z, (double)s.z, acc0[2], 0, 0, 0);
            acc1[2] = __builtin_amdgcn_mfma_f64_16x16x4f64((double)w1.z, (double)s.z, acc1[2], 0, 0, 0);
            acc0[3] = __builtin_amdgcn_mfma_f64_16x16x4f64((double)w0.w, (double)s.w, acc0[3], 0, 0, 0);
            acc1[3] = __builtin_amdgcn_mfma_f64_16x16x4f64((double)w1.w, (double)s.w, acc1[3], 0, 0, 0);
        }
    }

    double4v a0 = (acc0[0] + acc0[1]) + (acc0[2] + acc0[3]);
    double4v a1 = (acc1[0] + acc1[1]) + (acc1[2] + acc1[3]);

    {
        double* my = red + ((size_t)wq * 64 + lane) * 8;
        #pragma unroll
        for (int r = 0; r < 4; ++r) { my[r] = a0[r]; my[4 + r] = a1[r]; }
    }
    __syncthreads();
    if (wq < 2) {
        const int off = wq * 4;
        double a[4];
        #pragma unroll
        for (int r = 0; r < 4; ++r) {
            a[r] =  red[((size_t)0 * 64 + lane) * 8 + off + r];
            a[r] += red[((size_t)1 * 64 + lane) * 8 + off + r];
            a[r] += red[((size_t)2 * 64 + lane) * 8 + off + r];
            a[r] += red[((size_t)3 * 64 + lane) * 8 + off + r];
        }

        const double th = (double)thresholds[l];
        const int T = *Tptr;
        const float sc = isLast ? 1.0f : (1.0f / (float)T);
        double m0 = 0., m1 = 0., m2 = 0., m3 = 0.;
        int c0 = 0, c1 = 0, c2 = 0, c3 = 0;
        for (int tt = 0; tt < T; ++tt) {
            m0 += a[0]; if (m0 > th) { c0++; m0 -= th; }
            m1 += a[1]; if (m1 > th) { c1++; m1 -= th; }
            m2 += a[2]; if (m2 > th) { c2++; m2 -= th; }
            m3 += a[3]; if (m3 > th) { c3++; m3 -= th; }
        }
        int cnt[4] = {c0, c1, c2, c3};
        #pragma unroll
        for (int r = 0; r < 4; ++r) {
            int n = n0 + 16 * wq + rowD[r];
            int b = btile * 16 + colD[r];
            dst[(size_t)n * BB + b] = (float)cnt[r] * sc;
            if (c8T) c8T[(size_t)b * NN + n] = (signed char)cnt[r];
        }
    }
}

// ---------------------------------------------------------------------------
// Integer-exact layer kernel (layers 1..3), base-128 digits, TILED operands.
//   sum_k W*cnt = sum_j 2^(7j-33) * acc_j  -  2.0 * acc_ones
// R5 change: K-loop is a #pragma unroll 1 PING-PONG (named stage buffers,
// exactly 2 chunks of fragments in flight) instead of full 8-chunk unroll.
// Theory: the full unroll exposed 88 independent loads -> hipcc hoisting ->
// VGPR spills to scratch (the 4-6x-over-roofline cost). Bounded liveness:
// 22 frags + 11 accs + addr ~= 150 VGPR, no spill; prefetch of chunk n+1
// issues before chunk n's MFMAs so L2 latency hides under matrix work.
// ---------------------------------------------------------------------------
__global__ __launch_bounds__(256, 2) void layer_i8_kernel(
    const signed char* __restrict__ B8,    // g8T tiled [ck:32][b:128][kk:64]
    const signed char* __restrict__ Wd5,   // 5 tiled digit planes, stride DP
    const float* __restrict__ thresholds, int l,
    const int*   __restrict__ Tptr,
    float* __restrict__ dst, signed char* __restrict__ c8T, int isLast)
{
    __shared__ double red[4 * 64 * 8];

    const int t    = threadIdx.x;
    const int wq   = t >> 6;
    const int lane = t & 63;
    const int q    = lane >> 4;
    const int c    = lane & 15;

    const int g     = blockIdx.x;
    const int btile = (g >> 3) & 7;
    const int nsup  = (g & 7) | ((g >> 6) << 3);
    const int n0    = nsup * 32;
    const int bcol  = btile * 16 + c;

    // ---- i8-native D-layout probe (R3-proven) ----
    int rowD[4], colD[4];
    {
        const int cb  = c * 0x01010101;     // every byte = c (label 0..15)
        const int hot = (q == 0) ? 1 : 0;   // single byte = 1 on q==0 lanes
        int4v aLab = {cb, cb, cb, cb};
        int4v oneh = {hot, 0, 0, 0};
        int4v dR = {0, 0, 0, 0}, dC = {0, 0, 0, 0};
        dR = __builtin_amdgcn_mfma_i32_16x16x64_i8(aLab, oneh, dR, 0, 0, 0);
        dC = __builtin_amdgcn_mfma_i32_16x16x64_i8(oneh, aLab, dC, 0, 0, 0);
        #pragma unroll
        for (int r = 0; r < 4; ++r) { rowD[r] = dR[r]; colD[r] = dC[r]; }
    }

    int4v acc0[NDIG], acc1[NDIG], accS = (int4v)0;
    #pragma unroll
    for (int j = 0; j < NDIG; ++j) { acc0[j] = (int4v)0; acc1[j] = (int4v)0; }

    const size_t DP = (size_t)NN * DD;
    // tiled bases: A fragment for lane (q,c) at tile offset c*64+q*16
    const signed char* ab = Wd5 + (size_t)nsup * 65536 + c * 64 + q * 16;
    const signed char* bb = B8 + bcol * 64 + q * 16;

    const int4v ones = {0x01010101, 0x01010101, 0x01010101, 0x01010101};
    const int ck0 = wq * 8;              // this quarter's first 64-k chunk

    // ping-pong stage buffers (named, statically indexed only)
    int4v A0[NDIG], A1[NDIG], Bv;        // even-chunk stage
    int4v N0[NDIG], N1[NDIG], Nb;        // odd-chunk stage

    // prologue: load chunk ck0 into A-stage
    {
        const signed char* ap = ab + (size_t)ck0 * 2048;
        #pragma unroll
        for (int j = 0; j < NDIG; ++j) {
            A0[j] = *(const int4v*)(ap + (size_t)j * DP);
            A1[j] = *(const int4v*)(ap + (size_t)j * DP + 1024);
        }
        Bv = *(const int4v*)(bb + (size_t)ck0 * 8192);
    }

    #pragma unroll 1
    for (int u = 0; u < 3; ++u) {        // chunks 2u, 2u+1 for u=0..2
        {   // prefetch odd chunk 2u+1 into N-stage
            const signed char* ap = ab + (size_t)(ck0 + 2 * u + 1) * 2048;
            #pragma unroll
            for (int j = 0; j < NDIG; ++j) {
                N0[j] = *(const int4v*)(ap + (size_t)j * DP);
                N1[j] = *(const int4v*)(ap + (size_t)j * DP + 1024);
            }
            Nb = *(const int4v*)(bb + (size_t)(ck0 + 2 * u + 1) * 8192);
        }
        #pragma unroll
        for (int j = 0; j < NDIG; ++j) {
            acc0[j] = __builtin_amdgcn_mfma_i32_16x16x64_i8(A0[j], Bv, acc0[j], 0, 0, 0);
            acc1[j] = __builtin_amdgcn_mfma_i32_16x16x64_i8(A1[j], Bv, acc1[j], 0, 0, 0);
        }
        accS = __builtin_amdgcn_mfma_i32_16x16x64_i8(ones, Bv, accS, 0, 0, 0);
        {   // prefetch even chunk 2u+2 into A-stage
            const signed char* ap = ab + (size_t)(ck0 + 2 * u + 2) * 2048;
            #pragma unroll
            for (int j = 0; j < NDIG; ++j) {
                A0[j] = *(const int4v*)(ap + (size_t)j * DP);
                A1[j] = *(const int4v*)(ap + (size_t)j * DP + 1024);
            }
            Bv = *(const int4v*)(bb + (size_t)(ck0 + 2 * u + 2) * 8192);
        }
        #pragma unroll
        for (int j = 0; j < NDIG; ++j) {
            acc0[j] = __builtin_amdgcn_mfma_i32_16x16x64_i8(N0[j], Nb, acc0[j], 0, 0, 0);
            acc1[j] = __builtin_amdgcn_mfma_i32_16x16x64_i8(N1[j], Nb, acc1[j], 0, 0, 0);
        }
        accS = __builtin_amdgcn_mfma_i32_16x16x64_i8(ones, Nb, accS, 0, 0, 0);
    }
    // epilogue: A-stage holds chunk 6; prefetch chunk 7, compute both
    {
        const signed char* ap = ab + (size_t)(ck0 + 7) * 2048;
        #pragma unroll
        for (int j = 0; j < NDIG; ++j) {
            N0[j] = *(const int4v*)(ap + (size_t)j * DP);
            N1[j] = *(const int4v*)(ap + (size_t)j * DP + 1024);
        }
        Nb = *(const int4v*)(bb + (size_t)(ck0 + 7) * 8192);
    }
    #pragma unroll
    for (int j = 0; j < NDIG; ++j) {
        acc0[j] = __builtin_amdgcn_mfma_i32_16x16x64_i8(A0[j], Bv, acc0[j], 0, 0, 0);
        acc1[j] = __builtin_amdgcn_mfma_i32_16x16x64_i8(A1[j], Bv, acc1[j], 0, 0, 0);
    }
    accS = __builtin_amdgcn_mfma_i32_16x16x64_i8(ones, Bv, accS, 0, 0, 0);
    #pragma unroll
    for (int j = 0; j < NDIG; ++j) {
        acc0[j] = __builtin_amdgcn_mfma_i32_16x16x64_i8(N0[j], Nb, acc0[j], 0, 0, 0);
        acc1[j] = __builtin_amdgcn_mfma_i32_16x16x64_i8(N1[j], Nb, acc1[j], 0, 0, 0);
    }
    accS = __builtin_amdgcn_mfma_i32_16x16x64_i8(ones, Nb, accS, 0, 0, 0);

    // digit recombination: exact powers of two; bias 2^34 removed via accS
    const double S0 = 0x1p-33, S1 = 0x1p-26, S2 = 0x1p-19,
                 S3 = 0x1p-12, S4 = 0x1p-5;
    {
        double* my = red + ((size_t)wq * 64 + lane) * 8;
        #pragma unroll
        for (int r = 0; r < 4; ++r) {
            double corr = 2.0 * (double)accS[r];
            my[r]     = S0 * (double)acc0[0][r] + S1 * (double)acc0[1][r]
                      + S2 * (double)acc0[2][r] + S3 * (double)acc0[3][r]
                      + S4 * (double)acc0[4][r] - corr;
            my[4 + r] = S0 * (double)acc1[0][r] + S1 * (double)acc1[1][r]
                      + S2 * (double)acc1[2][r] + S3 * (double)acc1[3][r]
                      + S4 * (double)acc1[4][r] - corr;
        }
    }
    __syncthreads();
    if (wq < 2) {
        const int off = wq * 4;
        double a[4];
        #pragma unroll
        for (int r = 0; r < 4; ++r) {
            a[r] =  red[((size_t)0 * 64 + lane) * 8 + off + r];
            a[r] += red[((size_t)1 * 64 + lane) * 8 + off + r];
            a[r] += red[((size_t)2 * 64 + lane) * 8 + off + r];
            a[r] += red[((size_t)3 * 64 + lane) * 8 + off + r];
        }

        const double th = (double)thresholds[l];
        const int T = *Tptr;
        const double invT = 1.0 / (double)T;
        const float sc = isLast ? 1.0f : (1.0f / (float)T);
        double m0 = 0., m1 = 0., m2 = 0., m3 = 0.;
        int c0 = 0, c1 = 0, c2 = 0, c3 = 0;
        const double v0 = a[0] * invT, v1 = a[1] * invT,
                     v2 = a[2] * invT, v3 = a[3] * invT;
        for (int tt = 0; tt < T; ++tt) {
            m0 += v0; if (m0 > th) { c0++; m0 -= th; }
            m1 += v1; if (m1 > th) { c1++; m1 -= th; }
            m2 += v2; if (m2 > th) { c2++; m2 -= th; }
            m3 += v3; if (m3 > th) { c3++; m3 -= th; }
        }
        int cnt[4] = {c0, c1, c2, c3};
        #pragma unroll
        for (int r = 0; r < 4; ++r) {
            int n = n0 + 16 * wq + rowD[r];
            int b = btile * 16 + colD[r];
            dst[(size_t)n * BB + b] = (float)cnt[r] * sc;
            if (c8T) c8T[(size_t)b * NN + n] = (signed char)cnt[r];
        }
    }
}

// ---------------------------------------------------------------------------
// Output gather: out[b, o] = cntT[out_idx[o]][b]
// ---------------------------------------------------------------------------
__global__ __launch_bounds__(256) void out_kernel(
    const float* __restrict__ cntT, const int* __restrict__ out_idx,
    float* __restrict__ out)
{
    int i = blockIdx.x * 256 + threadIdx.x;   // over BB*OUTN
    int b = i >> 10;
    int o = i & 1023;
    out[i] = cntT[(size_t)out_idx[o] * BB + b];
}

extern "C" void kernel_launch(void* const* d_in, const int* in_sizes, int n_in,
                              void* d_out, int out_size, void* d_ws, size_t ws_size,
                              hipStream_t stream)
{
    const float* x    = (const float*)d_in[0];
    const float* W    = (const float*)d_in[1];
    const float* thr  = (const float*)d_in[2];
    const int*   axon = (const int*)d_in[3];
    const int*   oidx = (const int*)d_in[4];
    const int*   Tptr = (const int*)d_in[5];
    float* out = (float*)d_out;

    const size_t DP = (size_t)NN * DD;
    char* ws = (char*)d_ws;
    float* At   = (float*)ws;                         // 1 MB [2048][128]
    float* mA   = (float*)(ws + (1u << 20));          // 1 MB ping
    float* mB   = (float*)(ws + (2u << 20));          // 1 MB pong
    float* cntT = (float*)(ws + (3u << 20));          // 1 MB
    signed char* c8A = (signed char*)(ws + (4u << 20));               // 256 KB [b][n]
    signed char* c8B = (signed char*)(ws + (4u << 20) + (256u << 10));// 256 KB
    signed char* g8T = (signed char*)(ws + (4u << 20) + (512u << 10));// 256 KB tiled
    signed char* Wd  = (signed char*)(ws + (5u << 20));               // 60 MB (3 layers x 5 planes)

    const int useI8 = (ws_size >= ((size_t)80 << 20)) ? 1 : 0;

    gather0_kernel<<<(DD * BB) / 256, 256, 0, stream>>>(x, axon, At);

    if (!useI8) {
        // fallback: proven all-fp64 path (round-0 structure)
        const float* srcs[LL] = { At, mA, mB, mA };
        float*       dsts[LL] = { mA, mB, mA, cntT };
        for (int l = 0; l < LL; ++l) {
            const int* idx = (l == 0) ? nullptr : (axon + (size_t)l * DD);
            layer_kernel<<<512, 256, 0, stream>>>(
                srcs[l], idx, W + (size_t)l * NN * DD, thr, l, Tptr,
                dsts[l], nullptr, (l == LL - 1) ? 1 : 0);
        }
    } else {
        // digitize W for layers 1..3 (one launch, tiled planes)
        wdig5_kernel<<<(int)(3 * (DP / 4) / 256), 256, 0, stream>>>(W + DP, Wd);

        // layer 0: fp64 MFMA path (fp32 x input), emits i8 counts to c8A
        layer_kernel<<<512, 256, 0, stream>>>(
            At, nullptr, W, thr, 0, Tptr, mA, c8A, 0);

        // layers 1..3: integer path, tiled operands
        signed char* c8s[3] = { c8A, c8B, c8A };
        signed char* c8d[3] = { c8B, c8A, nullptr };
        float*       fds[3] = { mB, mA, cntT };
        for (int l = 1; l < LL; ++l) {
            gather8_kernel<<<(BB * DD / 4) / 256, 256, 0, stream>>>(
                c8s[l - 1], axon + (size_t)l * DD, g8T);
            layer_i8_kernel<<<512, 256, 0, stream>>>(
                g8T, Wd + (size_t)(l - 1) * 5 * DP, thr, l, Tptr,
                fds[l - 1], c8d[l - 1], (l == LL - 1) ? 1 : 0);
        }
    }

    out_kernel<<<(BB * OUTN) / 256, 256, 0, stream>>>(cntT, oidx, out);
}